// Round 12
// baseline (147.836 us; speedup 1.0000x reference)
//
#include <hip/hip_runtime.h>
#include <hip/hip_bf16.h>

// Problem constants (fixed by reference)
#define B_    4
#define Qn_   2048
#define S_    21760   // 128*128 + 64*64 + 32*32 + 16*16

typedef short  bfx4    __attribute__((ext_vector_type(4)));
typedef short  short8  __attribute__((ext_vector_type(8)));
typedef float  floatx4 __attribute__((ext_vector_type(4)));

__device__ __forceinline__ unsigned short f2bf(float f) {
    unsigned int u = __builtin_bit_cast(unsigned int, f);
    u += 0x7fffu + ((u >> 16) & 1u);   // round-to-nearest-even
    return (unsigned short)(u >> 16);
}
__device__ __forceinline__ float bf2f(unsigned short h) {
    unsigned int u = ((unsigned int)h) << 16;
    return __builtin_bit_cast(float, u);
}

// packed f32x8 -> bf16x8 via v_cvt_pk_bf16_f32 (RNE, 1 instr / 2 elems)
__device__ __forceinline__ short8 cvt_pk8(floatx4 f0, floatx4 f1) {
    union { unsigned int u[4]; short8 s; } r;
    asm("v_cvt_pk_bf16_f32 %0, %1, %2" : "=v"(r.u[0]) : "v"(f0[0]), "v"(f0[1]));
    asm("v_cvt_pk_bf16_f32 %0, %1, %2" : "=v"(r.u[1]) : "v"(f0[2]), "v"(f0[3]));
    asm("v_cvt_pk_bf16_f32 %0, %1, %2" : "=v"(r.u[2]) : "v"(f1[0]), "v"(f1[1]));
    asm("v_cvt_pk_bf16_f32 %0, %1, %2" : "=v"(r.u[3]) : "v"(f1[2]), "v"(f1[3]));
    return r.s;
}

// async global->LDS, 16B per lane. lds must be WAVE-UNIFORM base (lane*16 implicit).
__device__ __forceinline__ void async16(void* lds, const void* g) {
    __builtin_amdgcn_global_load_lds(
        (const __attribute__((address_space(1))) unsigned int*)g,
        (__attribute__((address_space(3))) unsigned int*)lds, 16, 0, 0);
}

template<int N>
__device__ __forceinline__ void wait_vm_lgkm0() {
    asm volatile("s_waitcnt vmcnt(%0) lgkmcnt(0)" :: "n"(N) : "memory");
}

// ---------------------------------------------------------------------------
// Prep 1: W_out -> bf16 NxK (Wot); [W_off|W_attn] -> bf16 NxK (Wcat); biases.
// ---------------------------------------------------------------------------
__global__ __launch_bounds__(640) void prep_w(
        const float* __restrict__ Wo,
        const float* __restrict__ Woff, const float* __restrict__ Wattn,
        const float* __restrict__ boff, const float* __restrict__ battn,
        short* __restrict__ Wot, short* __restrict__ Wcat,
        float* __restrict__ bcat) {
    const int k = blockIdx.x;      // 0..255
    const int t = threadIdx.x;
    if (t < 256) {
        Wot[t * 256 + k] = (short)f2bf(Wo[k * 256 + t]);
    } else {
        const int n = t - 256;     // 0..383
        const float w = (n < 256) ? Woff[k * 256 + n] : Wattn[k * 128 + (n - 256)];
        Wcat[n * 256 + k] = (short)f2bf(w);
    }
    if (blockIdx.x == 0 && t < 384)
        bcat[t] = (t < 256) ? boff[t] : battn[t - 256];
}

// ---------------------------------------------------------------------------
// Prep 2: W_val (256x256 f32, KxN) -> bf16 FRAGMENT order:
//   Wf[((kc*16 + nf)*64 + lane)*8 + j] = W[kc*32 + (lane>>4)*8 + j][nf*16 + (lane&15)]
//   -> a wave's B-fragment (kc,nf) is a contiguous 1KB dwordx4 load at lane*16.
// ---------------------------------------------------------------------------
__global__ __launch_bounds__(1024) void prep_wfrag(const float* __restrict__ W,
                                                   short* __restrict__ Wf) {
    const int g = blockIdx.x * 1024 + threadIdx.x;   // 0..65535
    const int j  = g & 7;
    const int l  = (g >> 3) & 63;
    const int nf = (g >> 9) & 15;
    const int kc = g >> 13;
    const int k = kc * 32 + (l >> 4) * 8 + j;
    const int n = nf * 16 + (l & 15);
    Wf[g] = (short)f2bf(W[k * 256 + n]);
}

// ---------------------------------------------------------------------------
// gemm_breg2: B-IN-REGISTERS streaming GEMM (fixed r11 spill).
//   512 persistent blocks x 512 thr (8 waves).  Wave cs owns 32 output cols:
//   bfrag[8][2] = 64 VGPRs, loaded ONCE from L2-resident Wf; an asm memory
//   clobber after the load BLOCKS rematerialization (r11: VGPR=100 < 128
//   needed proved the compiler re-fetched B from L2 inside the loop).
//   Grid-stride over 16-row tiles; 8 waves share the same A rows (L1 reuse).
//   ZERO LDS, ZERO barriers: per tile 8+8 half-batched A loads, cvt_pk,
//   16 register-operand MFMAs, 2 row-major bfx4 stores.
//   Swapped MFMA: D row = rowbase+l16, col = (cs*2+nf)*16 + lq*4 + reg.
// ---------------------------------------------------------------------------
__global__ __launch_bounds__(512, 4) void gemm_breg2(
        const float* __restrict__ Av, const short* __restrict__ Wf,
        const float* __restrict__ bias, short* __restrict__ Cv, int ntiles) {
    const int tid  = threadIdx.x;
    const int lane = tid & 63, cs = tid >> 6;    // col-split wave 0..7
    const int l16  = lane & 15, lq = lane >> 4;

    // --- B slice into registers: 8 kc x 2 nf fragments (64 VGPRs) ---
    short8 bfrag[8][2];
#pragma unroll
    for (int kc = 0; kc < 8; ++kc)
#pragma unroll
        for (int nf = 0; nf < 2; ++nf)
            bfrag[kc][nf] = *(const short8*)(
                Wf + (long)((kc * 16 + cs * 2 + nf) * 64 + lane) * 8);

    floatx4 bv4[2];
#pragma unroll
    for (int nf = 0; nf < 2; ++nf)
        bv4[nf] = *(const floatx4*)(bias + (cs * 2 + nf) * 16 + lq * 4);

    asm volatile("" ::: "memory");   // block rematerialization of B/bias loads

    // --- barrier-free tile stream ---
    for (int t = blockIdx.x; t < ntiles; t += (int)gridDim.x) {
        const long rowbase = (long)t * 16;
        const float* ap = Av + (rowbase + l16) * 256 + lq * 8;

        floatx4 g0[4], g1[4];
        short8  a16[4];

        // H0: 8 loads (kc 0..3)
#pragma unroll
        for (int kc = 0; kc < 4; ++kc) {
            g0[kc] = *(const floatx4*)(ap + kc * 32);
            g1[kc] = *(const floatx4*)(ap + kc * 32 + 4);
        }
#pragma unroll
        for (int kc = 0; kc < 4; ++kc) a16[kc] = cvt_pk8(g0[kc], g1[kc]);

        // H1: 8 loads (kc 4..7), in flight under H0's MFMAs
#pragma unroll
        for (int kc = 0; kc < 4; ++kc) {
            g0[kc] = *(const floatx4*)(ap + (kc + 4) * 32);
            g1[kc] = *(const floatx4*)(ap + (kc + 4) * 32 + 4);
        }

        floatx4 acc[2];
#pragma unroll
        for (int nf = 0; nf < 2; ++nf) acc[nf] = (floatx4){0.f, 0.f, 0.f, 0.f};

#pragma unroll
        for (int kc = 0; kc < 4; ++kc)
#pragma unroll
            for (int nf = 0; nf < 2; ++nf)
                acc[nf] = __builtin_amdgcn_mfma_f32_16x16x32_bf16(
                    bfrag[kc][nf], a16[kc], acc[nf], 0, 0, 0);

#pragma unroll
        for (int kc = 0; kc < 4; ++kc) a16[kc] = cvt_pk8(g0[kc], g1[kc]);
#pragma unroll
        for (int kc = 0; kc < 4; ++kc)
#pragma unroll
            for (int nf = 0; nf < 2; ++nf)
                acc[nf] = __builtin_amdgcn_mfma_f32_16x16x32_bf16(
                    bfrag[kc + 4][nf], a16[kc], acc[nf], 0, 0, 0);

        short* co = Cv + (rowbase + l16) * 256 + cs * 32 + lq * 4;
#pragma unroll
        for (int nf = 0; nf < 2; ++nf) {
            const floatx4 v = acc[nf] + bv4[nf];
            bfx4 s;
#pragma unroll
            for (int r = 0; r < 4; ++r) s[r] = (short)f2bf(v[r]);
            *(bfx4*)(co + nf * 16) = s;
        }
    }
}

// ---------------------------------------------------------------------------
// gemm_v8 (round-8, kept for the out GEMM; A bf16, out f32)
// ---------------------------------------------------------------------------
template<int A_BF16, int OUT_F32>
__global__ __launch_bounds__(256) void gemm_v8(
        const void* __restrict__ Av, const short* __restrict__ Bt,
        const float* __restrict__ bias, void* __restrict__ Cv) {
    constexpr int VM = A_BF16 ? 1 : 2;
    __shared__ short As[2][64 * 32];
    __shared__ short Bs[2][256 * 32];

    const int tid  = threadIdx.x;
    const int lane = tid & 63, wave = tid >> 6;
    const int l16  = lane & 15, lq = lane >> 4;
    const long row0 = (long)blockIdx.x * 64;
    const int  r_a = tid >> 2, c_a = tid & 3;

    floatx4 sA0[2], sA1[2];
    short8  sB16[2];

    auto loadA = [&](int kk, int s) {
        if (A_BF16) {
            sB16[s] = *(const short8*)((const short*)Av + (row0 + r_a) * 256 + kk * 32 + c_a * 8);
        } else {
            const float* g = (const float*)Av + (row0 + r_a) * 256 + kk * 32 + c_a * 8;
            sA0[s] = *(const floatx4*)g;
            sA1[s] = *(const floatx4*)(g + 4);
        }
    };
    auto writeA = [&](int buf, int s) {
        short8 v;
        if (A_BF16) v = sB16[s];
        else        v = cvt_pk8(sA0[s], sA1[s]);
        *(short8*)&As[buf][r_a * 32 + ((c_a ^ (r_a & 3)) << 3)] = v;
    };
    auto stageB = [&](int kk, int buf) {
#pragma unroll
        for (int c2 = 0; c2 < 4; ++c2) {
            const int idx = c2 * 256 + tid;
            const int r = idx >> 2, ch = idx & 3;
            const short* g = Bt + (long)r * 256 + kk * 32 + ((ch ^ (r & 3)) << 3);
            async16(&Bs[buf][(c2 * 256 + (wave << 6)) * 8], g);
        }
    };

    floatx4 acc[4][4];
#pragma unroll
    for (int i = 0; i < 4; ++i)
#pragma unroll
        for (int j = 0; j < 4; ++j) acc[i][j] = (floatx4){0.f, 0.f, 0.f, 0.f};

    auto compute = [&](int buf) {
        short8 af[4], bv[4];
#pragma unroll
        for (int mf = 0; mf < 4; ++mf) {
            const int r = mf * 16 + l16;
            af[mf] = *(const short8*)&As[buf][r * 32 + ((lq ^ (r & 3)) << 3)];
        }
#pragma unroll
        for (int nf = 0; nf < 4; ++nf) {
            const int r = wave * 64 + nf * 16 + l16;
            bv[nf] = *(const short8*)&Bs[buf][r * 32 + ((lq ^ (r & 3)) << 3)];
        }
#pragma unroll
        for (int mf = 0; mf < 4; ++mf)
#pragma unroll
            for (int nf = 0; nf < 4; ++nf)
                acc[mf][nf] = __builtin_amdgcn_mfma_f32_16x16x32_bf16(
                    bv[nf], af[mf], acc[mf][nf], 0, 0, 0);
    };

    stageB(0, 0);
    loadA(0, 0);
    loadA(1, 1);
    writeA(0, 0);
    wait_vm_lgkm0<VM>();
    __builtin_amdgcn_s_barrier();
    __builtin_amdgcn_sched_barrier(0);

#pragma unroll
    for (int k = 0; k < 7; ++k) {
        const int cur = k & 1, nxt = cur ^ 1;
        stageB(k + 1, nxt);
        if (k < 6) loadA(k + 2, k & 1);
        compute(cur);
        writeA(nxt, (k + 1) & 1);
        if (k < 6) wait_vm_lgkm0<VM>();
        else       wait_vm_lgkm0<0>();
        __builtin_amdgcn_s_barrier();
        __builtin_amdgcn_sched_barrier(0);
    }
    compute(1);

#pragma unroll
    for (int mf = 0; mf < 4; ++mf) {
        const long grow = row0 + mf * 16 + l16;
#pragma unroll
        for (int nf = 0; nf < 4; ++nf) {
            const int gcol = wave * 64 + nf * 16 + lq * 4;
            const floatx4 bv4 = *(const floatx4*)(bias + gcol);
            const floatx4 v = acc[mf][nf] + bv4;
            if (OUT_F32) {
                *(floatx4*)((float*)Cv + grow * 256 + gcol) = v;
            } else {
                bfx4 s;
#pragma unroll
                for (int r = 0; r < 4; ++r) s[r] = (short)f2bf(v[r]);
                *(bfx4*)((short*)Cv + grow * 256 + gcol) = s;
            }
        }
    }
}

// ---------------------------------------------------------------------------
// gemm_tile (round-4 structure, kept for the 384-col offattn GEMM)
// ---------------------------------------------------------------------------
template<int NW, int A_BF16, int OUT_F32>
__global__ __launch_bounds__(NW * 128) void gemm_tile(
        const void* __restrict__ Av, const short* __restrict__ Bt,
        const float* __restrict__ bias, void* __restrict__ Cv, int Ntot) {
    constexpr int NT = NW * 128;
    constexpr int BN = NW * 64;
    constexpr int AIT = (512 + NT - 1) / NT;
    __shared__ short As[2][128 * 32];
    __shared__ short Bs[2][BN * 32];

    const int tid  = threadIdx.x;
    const int lane = tid & 63, wave = tid >> 6;
    const int l16  = lane & 15, lq = lane >> 4;
    const int wr   = wave / NW, wc = wave % NW;
    const long row0 = (long)blockIdx.x * 128;
    const int  col0 = blockIdx.y * BN;

    floatx4 acc[4][4];
#pragma unroll
    for (int i = 0; i < 4; ++i)
#pragma unroll
        for (int j = 0; j < 4; ++j) acc[i][j] = (floatx4){0.f, 0.f, 0.f, 0.f};

    floatx4 a0[AIT], a1[AIT];

    auto loadA = [&](int kk) {
#pragma unroll
        for (int it = 0; it < AIT; ++it) {
            const int i = tid + it * NT;
            if (i < 512) {
                const int r = i >> 2, c = i & 3;
                const float* g = (const float*)Av + (row0 + r) * 256 + kk * 32 + c * 8;
                a0[it] = *(const floatx4*)g;
                a1[it] = *(const floatx4*)(g + 4);
            }
        }
    };
    auto writeA = [&](int bb) {
#pragma unroll
        for (int it = 0; it < AIT; ++it) {
            const int i = tid + it * NT;
            if (i < 512) {
                const int r = i >> 2, c = i & 3;
                *(short8*)&As[bb][r * 32 + ((c ^ (r & 3)) << 3)] = cvt_pk8(a0[it], a1[it]);
            }
        }
    };
    auto stageB = [&](int kk, int bb) {
#pragma unroll
        for (int c2 = 0; c2 < 2; ++c2) {
            const int idx = c2 * NT + tid;
            const int r = idx >> 2, ch = idx & 3;
            const short* g = Bt + (long)(col0 + r) * 256 + kk * 32 + ((ch ^ (r & 3)) << 3);
            async16(&Bs[bb][(c2 * NT + (wave << 6)) * 8], g);
        }
    };

    loadA(0);
    stageB(0, 0);
    writeA(0);
    __syncthreads();

    int buf = 0;
    for (int kk = 0; kk < 8; ++kk) {
        const int nxt = buf ^ 1;
        if (kk < 7) {
            loadA(kk + 1);
            stageB(kk + 1, nxt);
        }
        short8 af[4], bv[4];
#pragma unroll
        for (int mf = 0; mf < 4; ++mf) {
            const int r = wr * 64 + mf * 16 + l16;
            af[mf] = *(const short8*)&As[buf][r * 32 + ((lq ^ (r & 3)) << 3)];
        }
#pragma unroll
        for (int nf = 0; nf < 4; ++nf) {
            const int r = wc * 64 + nf * 16 + l16;
            bv[nf] = *(const short8*)&Bs[buf][r * 32 + ((lq ^ (r & 3)) << 3)];
        }
#pragma unroll
        for (int mf = 0; mf < 4; ++mf)
#pragma unroll
            for (int nf = 0; nf < 4; ++nf)
                acc[mf][nf] = __builtin_amdgcn_mfma_f32_16x16x32_bf16(af[mf], bv[nf], acc[mf][nf], 0, 0, 0);
        if (kk < 7) writeA(nxt);
        __syncthreads();
        buf = nxt;
    }

#pragma unroll
    for (int nf = 0; nf < 4; ++nf) {
        const int col = col0 + wc * 64 + nf * 16 + l16;
        const float bvl = bias[col];
#pragma unroll
        for (int mf = 0; mf < 4; ++mf)
#pragma unroll
            for (int r = 0; r < 4; ++r) {
                const long row = row0 + wr * 64 + mf * 16 + lq * 4 + r;
                const float v = acc[mf][nf][r] + bvl;
                if (OUT_F32) ((float*)Cv)[row * Ntot + col] = v;
                else         ((short*)Cv)[row * Ntot + col] = (short)f2bf(v);
            }
    }
}

// ---------------------------------------------------------------------------
// Sampler: softmax + deformable bilinear gather -> wv (bf16)  (round-8)
// ---------------------------------------------------------------------------
__global__ __launch_bounds__(512) void sampler(
        const float* __restrict__ priors,
        const int* __restrict__ shapes, const int* __restrict__ starts,
        const float* __restrict__ offattn,
        const short* __restrict__ value, short* __restrict__ wv) {
    __shared__ float oa_lds[16][384];
    __shared__ float pri_lds[16][4][2];
    __shared__ int   shp_lds[4][2];
    __shared__ int   st_lds[4];

    const int tid = threadIdx.x;
    const int b   = blockIdx.x >> 7;
    const int qt  = blockIdx.x & 127;
    const long q0 = (long)qt * 16;

    const float* src = offattn + ((long)b * Qn_ + q0) * 384;
    for (int i = tid; i < 16 * 384 / 4; i += 512)
        ((floatx4*)oa_lds)[i] = ((const floatx4*)src)[i];
    if (tid < 128) ((float*)pri_lds)[tid] = priors[((long)b * Qn_ + q0) * 8 + tid];
    if (tid < 8)  ((int*)shp_lds)[tid] = shapes[tid];
    if (tid < 4)  st_lds[tid] = starts[tid];
    __syncthreads();

    if (tid < 128) {
        const int qi = tid >> 3, h = tid & 7;
        float* a = &oa_lds[qi][256 + h * 16];
        float m = a[0];
        for (int i = 1; i < 16; ++i) m = fmaxf(m, a[i]);
        float s = 0.f;
        for (int i = 0; i < 16; ++i) { float e = expf(a[i] - m); a[i] = e; s += e; }
        const float inv = 1.f / s;
        for (int i = 0; i < 16; ++i) a[i] *= inv;
    }
    __syncthreads();

    const int pairi = tid >> 2, sub = tid & 3;
    const int qi = pairi >> 3, h = pairi & 7;
    float acc[8];
#pragma unroll
    for (int j = 0; j < 8; ++j) acc[j] = 0.f;
    const short* vbase = value + (long)b * S_ * 256 + h * 32 + sub * 8;

    for (int l = 0; l < 4; ++l) {
        const int Hl = shp_lds[l][0], Wl = shp_lds[l][1];
        const int st = st_lds[l];
        const float px = pri_lds[qi][l][0], py = pri_lds[qi][l][1];
        const float invW = 1.f / (float)Wl, invH = 1.f / (float)Hl;

        float wgt[16];
        int   off[16];
#pragma unroll
        for (int p = 0; p < 4; ++p) {
            const int cb = h * 16 + l * 4 + p;
            const float ox = oa_lds[qi][cb * 2], oy = oa_lds[qi][cb * 2 + 1];
            const float lx = px + ox * invW, ly = py + oy * invH;
            const float ix = lx * (float)Wl - 0.5f, iy = ly * (float)Hl - 0.5f;
            const float x0f = floorf(ix), y0f = floorf(iy);
            const int x0 = (int)x0f, y0 = (int)y0f;
            const float fx = ix - x0f, fy = iy - y0f;
            const float awv = oa_lds[qi][256 + cb];
#pragma unroll
            for (int dy = 0; dy < 2; ++dy) {
                const int yc = y0 + dy;
                const float wy = dy ? fy : 1.f - fy;
                const int yi = min(max(yc, 0), Hl - 1);
#pragma unroll
                for (int dx = 0; dx < 2; ++dx) {
                    const int xc = x0 + dx;
                    const float wx = dx ? fx : 1.f - fx;
                    const int xi = min(max(xc, 0), Wl - 1);
                    const bool v = (xc >= 0) & (xc < Wl) & (yc >= 0) & (yc < Hl);
                    const int j = p * 4 + dy * 2 + dx;
                    wgt[j] = v ? wy * wx * awv : 0.f;
                    off[j] = yi * Wl + xi;
                }
            }
        }
        const short* base = vbase + (long)st * 256;
        short8 vv[16];
#pragma unroll
        for (int j = 0; j < 16; ++j)
            vv[j] = *(const short8*)(base + (long)off[j] * 256);
#pragma unroll
        for (int j = 0; j < 16; ++j) {
            const float w = wgt[j];
#pragma unroll
            for (int c = 0; c < 8; ++c) acc[c] += w * bf2f((unsigned short)vv[j][c]);
        }
    }

    short8 ov;
#pragma unroll
    for (int j = 0; j < 8; ++j) ov[j] = (short)f2bf(acc[j]);
    *(short8*)(wv + (((long)b * Qn_ + q0 + qi) * 256 + h * 32 + sub * 8)) = ov;
}

// ---------------------------------------------------------------------------
extern "C" void kernel_launch(void* const* d_in, const int* in_sizes, int n_in,
                              void* d_out, int out_size, void* d_ws, size_t ws_size,
                              hipStream_t stream) {
    const float* in_feats = (const float*)d_in[0];
    const float* priors   = (const float*)d_in[1];
    const float* sfeats   = (const float*)d_in[2];
    const int*   shapes   = (const int*)d_in[3];
    const int*   starts   = (const int*)d_in[4];
    const float* W_off    = (const float*)d_in[5];
    const float* b_off    = (const float*)d_in[6];
    const float* W_attn   = (const float*)d_in[7];
    const float* b_attn   = (const float*)d_in[8];
    const float* W_val    = (const float*)d_in[9];
    const float* b_val    = (const float*)d_in[10];
    const float* W_out    = (const float*)d_in[11];
    const float* b_out    = (const float*)d_in[12];
    float* out = (float*)d_out;

    // Workspace: Wvt(frag) 128K | Wot 128K | Wcat 192K | value 44.56M | wv 4M
    //            offattn 12.58M | bcat 1.5K (f32)
    short* Wvt     = (short*)d_ws;
    short* Wot     = Wvt + 65536;
    short* Wcat    = Wot + 65536;
    short* value   = Wcat + 98304;
    short* wv      = value + (long)B_ * S_ * 256;
    float* offattn = (float*)(wv + (long)B_ * Qn_ * 256);
    float* bcat    = offattn + (long)B_ * Qn_ * 384;

    prep_w<<<256, 640, 0, stream>>>(W_out, W_off, W_attn, b_off, b_attn,
                                    Wot, Wcat, bcat);
    prep_wfrag<<<64, 1024, 0, stream>>>(W_val, Wvt);
    // value = sample_feats @ W_val + b_val   (87040 x 256), bf16 out
    gemm_breg2<<<512, 512, 0, stream>>>(sfeats, Wvt, b_val, value, (B_ * S_) / 16);
    // offattn = in_feats @ [W_off|W_attn] + bcat  (8192 x 384), f32 out
    gemm_tile<3, 0, 1><<<dim3((B_ * Qn_) / 128, 2), 384, 0, stream>>>(
        (const void*)in_feats, Wcat, bcat, (void*)offattn, 384);
    // softmax + deformable sampling
    sampler<<<B_ * (Qn_ / 16), 512, 0, stream>>>(priors, shapes, starts,
                                                 offattn, value, wv);
    // out = wv @ W_out + b_out   (8192 x 256), f32 out
    gemm_v8<1, 1><<<(B_ * Qn_) / 64, 256, 0, stream>>>(
        (const void*)wv, Wot, b_out, (void*)out);
}

// Round 13
// 98.601 us; speedup vs baseline: 1.4993x; 1.4993x over previous
//
#include <hip/hip_runtime.h>
#include <hip/hip_bf16.h>

// Problem constants (fixed by reference)
#define B_    4
#define Qn_   2048
#define S_    21760   // 128*128 + 64*64 + 32*32 + 16*16

typedef short  bfx4    __attribute__((ext_vector_type(4)));
typedef short  short8  __attribute__((ext_vector_type(8)));
typedef float  floatx4 __attribute__((ext_vector_type(4)));

__device__ __forceinline__ unsigned short f2bf(float f) {
    unsigned int u = __builtin_bit_cast(unsigned int, f);
    u += 0x7fffu + ((u >> 16) & 1u);   // round-to-nearest-even
    return (unsigned short)(u >> 16);
}
__device__ __forceinline__ float bf2f(unsigned short h) {
    unsigned int u = ((unsigned int)h) << 16;
    return __builtin_bit_cast(float, u);
}

// packed f32x8 -> bf16x8 via v_cvt_pk_bf16_f32 (RNE, 1 instr / 2 elems)
__device__ __forceinline__ short8 cvt_pk8(floatx4 f0, floatx4 f1) {
    union { unsigned int u[4]; short8 s; } r;
    asm("v_cvt_pk_bf16_f32 %0, %1, %2" : "=v"(r.u[0]) : "v"(f0[0]), "v"(f0[1]));
    asm("v_cvt_pk_bf16_f32 %0, %1, %2" : "=v"(r.u[1]) : "v"(f0[2]), "v"(f0[3]));
    asm("v_cvt_pk_bf16_f32 %0, %1, %2" : "=v"(r.u[2]) : "v"(f1[0]), "v"(f1[1]));
    asm("v_cvt_pk_bf16_f32 %0, %1, %2" : "=v"(r.u[3]) : "v"(f1[2]), "v"(f1[3]));
    return r.s;
}

// async global->LDS, 16B per lane. lds must be WAVE-UNIFORM base (lane*16 implicit).
__device__ __forceinline__ void async16(void* lds, const void* g) {
    __builtin_amdgcn_global_load_lds(
        (const __attribute__((address_space(1))) unsigned int*)g,
        (__attribute__((address_space(3))) unsigned int*)lds, 16, 0, 0);
}

template<int N>
__device__ __forceinline__ void wait_vm_lgkm0() {
    asm volatile("s_waitcnt vmcnt(%0) lgkmcnt(0)" :: "n"(N) : "memory");
}

// ---------------------------------------------------------------------------
// Prep: cast+transpose weights to bf16 NxK, concat off|attn, concat biases.
// ---------------------------------------------------------------------------
__global__ __launch_bounds__(896) void prep_w(
        const float* __restrict__ Wv, const float* __restrict__ Wo,
        const float* __restrict__ Woff, const float* __restrict__ Wattn,
        const float* __restrict__ boff, const float* __restrict__ battn,
        short* __restrict__ Wvt, short* __restrict__ Wot,
        short* __restrict__ Wcat, float* __restrict__ bcat) {
    const int k = blockIdx.x;      // 0..255
    const int t = threadIdx.x;
    if (t < 256) {
        Wvt[t * 256 + k] = (short)f2bf(Wv[k * 256 + t]);
    } else if (t < 512) {
        const int n = t - 256;
        Wot[n * 256 + k] = (short)f2bf(Wo[k * 256 + n]);
    } else {
        const int n = t - 512;     // 0..383
        const float w = (n < 256) ? Woff[k * 256 + n] : Wattn[k * 128 + (n - 256)];
        Wcat[n * 256 + k] = (short)f2bf(w);
    }
    if (blockIdx.x == 0 && t < 384)
        bcat[t] = (t < 256) ? boff[t] : battn[t - 256];
}

// ---------------------------------------------------------------------------
// gemm_ring: value GEMM with RING-3 LDS + DEPTH-2 DMA pipeline (T3+T4).
//   C[M x 256] = A[M x 256](f32) @ B + bias -> bf16.  BM=64, BN=256, 4 waves.
//   All staging via global_load_lds (A kept f32 in LDS, cvt on read):
//   per K-step each thread issues 6 DMAs (2 A + 4 B) for step k+2; the
//   barrier waits vmcnt(12) -> 12 DMA-instrs ALWAYS in flight, the read
//   queue never drains (r12 diagnosis: every prior variant's issue duty
//   cycle <=50% capped effective read BW at ~2.3 TB/s).
//   LDS: A f32 [64][32] x3 (8KB each), B bf16 [256][32] x3 (16KB) = 72KB.
//   16B-chunk XOR swizzles: A chunk ^= row&7, B chunk ^= col&3 (src + read).
//   Swapped MFMA -> row-major bfx4 stores (layout verified r6-r12).
// ---------------------------------------------------------------------------
__global__ __launch_bounds__(256, 4) void gemm_ring(
        const float* __restrict__ Av, const short* __restrict__ Bt,
        const float* __restrict__ bias, short* __restrict__ Cv) {
    __shared__ float Asl[3][64 * 32];    // 3 x 8 KB
    __shared__ short Bsl[3][256 * 32];   // 3 x 16 KB

    const int tid  = threadIdx.x;
    const int lane = tid & 63, wave = tid >> 6;
    const int l16  = lane & 15, lq = lane >> 4;
    const long row0 = (long)blockIdx.x * 64;

    auto stage = [&](int kk) {
        const int s = kk % 3;
#pragma unroll
        for (int i = 0; i < 2; ++i) {            // A: 512 chunks, 2/thread
            const int gc = i * 256 + tid;
            const int r = gc >> 3, c = gc & 7;
            const float* g = Av + (row0 + r) * 256 + kk * 32 + ((c ^ (r & 7)) << 2);
            async16((char*)&Asl[s][0] + i * 4096 + wave * 1024, g);
        }
#pragma unroll
        for (int i = 0; i < 4; ++i) {            // B: 1024 chunks, 4/thread
            const int gc = i * 256 + tid;
            const int col = gc >> 2, cc = gc & 3;
            const short* g = Bt + (long)col * 256 + kk * 32 + ((cc ^ (col & 3)) << 3);
            async16((char*)&Bsl[s][0] + i * 4096 + wave * 1024, g);
        }
    };

    floatx4 acc[4][4];
#pragma unroll
    for (int i = 0; i < 4; ++i)
#pragma unroll
        for (int j = 0; j < 4; ++j) acc[i][j] = (floatx4){0.f, 0.f, 0.f, 0.f};

    auto compute = [&](int kk) {
        const int s = kk % 3;
        short8 af[4], bv[4];
#pragma unroll
        for (int mf = 0; mf < 4; ++mf) {
            const int row = mf * 16 + l16;
            const int x = row & 7;
            floatx4 a0 = *(const floatx4*)((const char*)&Asl[s][0] + row * 128 + (((lq * 2)     ^ x) << 4));
            floatx4 a1 = *(const floatx4*)((const char*)&Asl[s][0] + row * 128 + (((lq * 2 + 1) ^ x) << 4));
            af[mf] = cvt_pk8(a0, a1);
        }
#pragma unroll
        for (int nf = 0; nf < 4; ++nf) {
            const int col = wave * 64 + nf * 16 + l16;
            bv[nf] = *(const short8*)((const char*)&Bsl[s][0] + col * 64 + ((lq ^ (col & 3)) << 4));
        }
#pragma unroll
        for (int mf = 0; mf < 4; ++mf)
#pragma unroll
            for (int nf = 0; nf < 4; ++nf)
                acc[mf][nf] = __builtin_amdgcn_mfma_f32_16x16x32_bf16(
                    bv[nf], af[mf], acc[mf][nf], 0, 0, 0);   // swapped -> row-major D
    };

    // prologue: two steps in flight before first compute
    stage(0);
    stage(1);

#pragma unroll
    for (int kk = 0; kk < 8; ++kk) {
        if (kk < 6) stage(kk + 2);               // into slot (kk-1)%3 (freed)
        if (kk < 6)      wait_vm_lgkm0<12>();    // drain step kk only
        else if (kk == 6) wait_vm_lgkm0<6>();
        else              wait_vm_lgkm0<0>();
        __builtin_amdgcn_s_barrier();
        __builtin_amdgcn_sched_barrier(0);
        compute(kk);
        __builtin_amdgcn_sched_barrier(0);
        __builtin_amdgcn_s_barrier();            // slot free for overwrite
    }

    // epilogue: row-major bfx4 stores
#pragma unroll
    for (int mf = 0; mf < 4; ++mf) {
        const long grow = row0 + mf * 16 + l16;
#pragma unroll
        for (int nf = 0; nf < 4; ++nf) {
            const int gcol = wave * 64 + nf * 16 + lq * 4;
            const floatx4 bv4 = *(const floatx4*)(bias + gcol);
            const floatx4 v = acc[mf][nf] + bv4;
            bfx4 sx;
#pragma unroll
            for (int r = 0; r < 4; ++r) sx[r] = (short)f2bf(v[r]);
            *(bfx4*)(Cv + grow * 256 + gcol) = sx;
        }
    }
}

// ---------------------------------------------------------------------------
// gemm_v8 (round-8, kept for the out GEMM; A bf16, out f32)
// ---------------------------------------------------------------------------
template<int A_BF16, int OUT_F32>
__global__ __launch_bounds__(256) void gemm_v8(
        const void* __restrict__ Av, const short* __restrict__ Bt,
        const float* __restrict__ bias, void* __restrict__ Cv) {
    constexpr int VM = A_BF16 ? 1 : 2;
    __shared__ short As[2][64 * 32];
    __shared__ short Bs[2][256 * 32];

    const int tid  = threadIdx.x;
    const int lane = tid & 63, wave = tid >> 6;
    const int l16  = lane & 15, lq = lane >> 4;
    const long row0 = (long)blockIdx.x * 64;
    const int  r_a = tid >> 2, c_a = tid & 3;

    floatx4 sA0[2], sA1[2];
    short8  sB16[2];

    auto loadA = [&](int kk, int s) {
        if (A_BF16) {
            sB16[s] = *(const short8*)((const short*)Av + (row0 + r_a) * 256 + kk * 32 + c_a * 8);
        } else {
            const float* g = (const float*)Av + (row0 + r_a) * 256 + kk * 32 + c_a * 8;
            sA0[s] = *(const floatx4*)g;
            sA1[s] = *(const floatx4*)(g + 4);
        }
    };
    auto writeA = [&](int buf, int s) {
        short8 v;
        if (A_BF16) v = sB16[s];
        else        v = cvt_pk8(sA0[s], sA1[s]);
        *(short8*)&As[buf][r_a * 32 + ((c_a ^ (r_a & 3)) << 3)] = v;
    };
    auto stageB = [&](int kk, int buf) {
#pragma unroll
        for (int c2 = 0; c2 < 4; ++c2) {
            const int idx = c2 * 256 + tid;
            const int r = idx >> 2, ch = idx & 3;
            const short* g = Bt + (long)r * 256 + kk * 32 + ((ch ^ (r & 3)) << 3);
            async16(&Bs[buf][(c2 * 256 + (wave << 6)) * 8], g);
        }
    };

    floatx4 acc[4][4];
#pragma unroll
    for (int i = 0; i < 4; ++i)
#pragma unroll
        for (int j = 0; j < 4; ++j) acc[i][j] = (floatx4){0.f, 0.f, 0.f, 0.f};

    auto compute = [&](int buf) {
        short8 af[4], bv[4];
#pragma unroll
        for (int mf = 0; mf < 4; ++mf) {
            const int r = mf * 16 + l16;
            af[mf] = *(const short8*)&As[buf][r * 32 + ((lq ^ (r & 3)) << 3)];
        }
#pragma unroll
        for (int nf = 0; nf < 4; ++nf) {
            const int r = wave * 64 + nf * 16 + l16;
            bv[nf] = *(const short8*)&Bs[buf][r * 32 + ((lq ^ (r & 3)) << 3)];
        }
#pragma unroll
        for (int mf = 0; mf < 4; ++mf)
#pragma unroll
            for (int nf = 0; nf < 4; ++nf)
                acc[mf][nf] = __builtin_amdgcn_mfma_f32_16x16x32_bf16(
                    bv[nf], af[mf], acc[mf][nf], 0, 0, 0);
    };

    stageB(0, 0);
    loadA(0, 0);
    loadA(1, 1);
    writeA(0, 0);
    wait_vm_lgkm0<VM>();
    __builtin_amdgcn_s_barrier();
    __builtin_amdgcn_sched_barrier(0);

#pragma unroll
    for (int k = 0; k < 7; ++k) {
        const int cur = k & 1, nxt = cur ^ 1;
        stageB(k + 1, nxt);
        if (k < 6) loadA(k + 2, k & 1);
        compute(cur);
        writeA(nxt, (k + 1) & 1);
        if (k < 6) wait_vm_lgkm0<VM>();
        else       wait_vm_lgkm0<0>();
        __builtin_amdgcn_s_barrier();
        __builtin_amdgcn_sched_barrier(0);
    }
    compute(1);

#pragma unroll
    for (int mf = 0; mf < 4; ++mf) {
        const long grow = row0 + mf * 16 + l16;
#pragma unroll
        for (int nf = 0; nf < 4; ++nf) {
            const int gcol = wave * 64 + nf * 16 + lq * 4;
            const floatx4 bv4 = *(const floatx4*)(bias + gcol);
            const floatx4 v = acc[mf][nf] + bv4;
            if (OUT_F32) {
                *(floatx4*)((float*)Cv + grow * 256 + gcol) = v;
            } else {
                bfx4 s;
#pragma unroll
                for (int r = 0; r < 4; ++r) s[r] = (short)f2bf(v[r]);
                *(bfx4*)((short*)Cv + grow * 256 + gcol) = s;
            }
        }
    }
}

// ---------------------------------------------------------------------------
// gemm_tile (round-4 structure, kept for the 384-col offattn GEMM)
// ---------------------------------------------------------------------------
template<int NW, int A_BF16, int OUT_F32>
__global__ __launch_bounds__(NW * 128) void gemm_tile(
        const void* __restrict__ Av, const short* __restrict__ Bt,
        const float* __restrict__ bias, void* __restrict__ Cv, int Ntot) {
    constexpr int NT = NW * 128;
    constexpr int BN = NW * 64;
    constexpr int AIT = (512 + NT - 1) / NT;
    __shared__ short As[2][128 * 32];
    __shared__ short Bs[2][BN * 32];

    const int tid  = threadIdx.x;
    const int lane = tid & 63, wave = tid >> 6;
    const int l16  = lane & 15, lq = lane >> 4;
    const int wr   = wave / NW, wc = wave % NW;
    const long row0 = (long)blockIdx.x * 128;
    const int  col0 = blockIdx.y * BN;

    floatx4 acc[4][4];
#pragma unroll
    for (int i = 0; i < 4; ++i)
#pragma unroll
        for (int j = 0; j < 4; ++j) acc[i][j] = (floatx4){0.f, 0.f, 0.f, 0.f};

    floatx4 a0[AIT], a1[AIT];

    auto loadA = [&](int kk) {
#pragma unroll
        for (int it = 0; it < AIT; ++it) {
            const int i = tid + it * NT;
            if (i < 512) {
                const int r = i >> 2, c = i & 3;
                const float* g = (const float*)Av + (row0 + r) * 256 + kk * 32 + c * 8;
                a0[it] = *(const floatx4*)g;
                a1[it] = *(const floatx4*)(g + 4);
            }
        }
    };
    auto writeA = [&](int bb) {
#pragma unroll
        for (int it = 0; it < AIT; ++it) {
            const int i = tid + it * NT;
            if (i < 512) {
                const int r = i >> 2, c = i & 3;
                *(short8*)&As[bb][r * 32 + ((c ^ (r & 3)) << 3)] = cvt_pk8(a0[it], a1[it]);
            }
        }
    };
    auto stageB = [&](int kk, int bb) {
#pragma unroll
        for (int c2 = 0; c2 < 2; ++c2) {
            const int idx = c2 * NT + tid;
            const int r = idx >> 2, ch = idx & 3;
            const short* g = Bt + (long)(col0 + r) * 256 + kk * 32 + ((ch ^ (r & 3)) << 3);
            async16(&Bs[bb][(c2 * NT + (wave << 6)) * 8], g);
        }
    };

    loadA(0);
    stageB(0, 0);
    writeA(0);
    __syncthreads();

    int buf = 0;
    for (int kk = 0; kk < 8; ++kk) {
        const int nxt = buf ^ 1;
        if (kk < 7) {
            loadA(kk + 1);
            stageB(kk + 1, nxt);
        }
        short8 af[4], bv[4];
#pragma unroll
        for (int mf = 0; mf < 4; ++mf) {
            const int r = wr * 64 + mf * 16 + l16;
            af[mf] = *(const short8*)&As[buf][r * 32 + ((lq ^ (r & 3)) << 3)];
        }
#pragma unroll
        for (int nf = 0; nf < 4; ++nf) {
            const int r = wc * 64 + nf * 16 + l16;
            bv[nf] = *(const short8*)&Bs[buf][r * 32 + ((lq ^ (r & 3)) << 3)];
        }
#pragma unroll
        for (int mf = 0; mf < 4; ++mf)
#pragma unroll
            for (int nf = 0; nf < 4; ++nf)
                acc[mf][nf] = __builtin_amdgcn_mfma_f32_16x16x32_bf16(af[mf], bv[nf], acc[mf][nf], 0, 0, 0);
        if (kk < 7) writeA(nxt);
        __syncthreads();
        buf = nxt;
    }

#pragma unroll
    for (int nf = 0; nf < 4; ++nf) {
        const int col = col0 + wc * 64 + nf * 16 + l16;
        const float bvl = bias[col];
#pragma unroll
        for (int mf = 0; mf < 4; ++mf)
#pragma unroll
            for (int r = 0; r < 4; ++r) {
                const long row = row0 + wr * 64 + mf * 16 + lq * 4 + r;
                const float v = acc[mf][nf][r] + bvl;
                if (OUT_F32) ((float*)Cv)[row * Ntot + col] = v;
                else         ((short*)Cv)[row * Ntot + col] = (short)f2bf(v);
            }
    }
}

// ---------------------------------------------------------------------------
// Sampler: softmax + deformable bilinear gather -> wv (bf16)  (round-8)
// ---------------------------------------------------------------------------
__global__ __launch_bounds__(512) void sampler(
        const float* __restrict__ priors,
        const int* __restrict__ shapes, const int* __restrict__ starts,
        const float* __restrict__ offattn,
        const short* __restrict__ value, short* __restrict__ wv) {
    __shared__ float oa_lds[16][384];
    __shared__ float pri_lds[16][4][2];
    __shared__ int   shp_lds[4][2];
    __shared__ int   st_lds[4];

    const int tid = threadIdx.x;
    const int b   = blockIdx.x >> 7;
    const int qt  = blockIdx.x & 127;
    const long q0 = (long)qt * 16;

    const float* src = offattn + ((long)b * Qn_ + q0) * 384;
    for (int i = tid; i < 16 * 384 / 4; i += 512)
        ((floatx4*)oa_lds)[i] = ((const floatx4*)src)[i];
    if (tid < 128) ((float*)pri_lds)[tid] = priors[((long)b * Qn_ + q0) * 8 + tid];
    if (tid < 8)  ((int*)shp_lds)[tid] = shapes[tid];
    if (tid < 4)  st_lds[tid] = starts[tid];
    __syncthreads();

    if (tid < 128) {
        const int qi = tid >> 3, h = tid & 7;
        float* a = &oa_lds[qi][256 + h * 16];
        float m = a[0];
        for (int i = 1; i < 16; ++i) m = fmaxf(m, a[i]);
        float s = 0.f;
        for (int i = 0; i < 16; ++i) { float e = expf(a[i] - m); a[i] = e; s += e; }
        const float inv = 1.f / s;
        for (int i = 0; i < 16; ++i) a[i] *= inv;
    }
    __syncthreads();

    const int pairi = tid >> 2, sub = tid & 3;
    const int qi = pairi >> 3, h = pairi & 7;
    float acc[8];
#pragma unroll
    for (int j = 0; j < 8; ++j) acc[j] = 0.f;
    const short* vbase = value + (long)b * S_ * 256 + h * 32 + sub * 8;

    for (int l = 0; l < 4; ++l) {
        const int Hl = shp_lds[l][0], Wl = shp_lds[l][1];
        const int st = st_lds[l];
        const float px = pri_lds[qi][l][0], py = pri_lds[qi][l][1];
        const float invW = 1.f / (float)Wl, invH = 1.f / (float)Hl;

        float wgt[16];
        int   off[16];
#pragma unroll
        for (int p = 0; p < 4; ++p) {
            const int cb = h * 16 + l * 4 + p;
            const float ox = oa_lds[qi][cb * 2], oy = oa_lds[qi][cb * 2 + 1];
            const float lx = px + ox * invW, ly = py + oy * invH;
            const float ix = lx * (float)Wl - 0.5f, iy = ly * (float)Hl - 0.5f;
            const float x0f = floorf(ix), y0f = floorf(iy);
            const int x0 = (int)x0f, y0 = (int)y0f;
            const float fx = ix - x0f, fy = iy - y0f;
            const float awv = oa_lds[qi][256 + cb];
#pragma unroll
            for (int dy = 0; dy < 2; ++dy) {
                const int yc = y0 + dy;
                const float wy = dy ? fy : 1.f - fy;
                const int yi = min(max(yc, 0), Hl - 1);
#pragma unroll
                for (int dx = 0; dx < 2; ++dx) {
                    const int xc = x0 + dx;
                    const float wx = dx ? fx : 1.f - fx;
                    const int xi = min(max(xc, 0), Wl - 1);
                    const bool v = (xc >= 0) & (xc < Wl) & (yc >= 0) & (yc < Hl);
                    const int j = p * 4 + dy * 2 + dx;
                    wgt[j] = v ? wy * wx * awv : 0.f;
                    off[j] = yi * Wl + xi;
                }
            }
        }
        const short* base = vbase + (long)st * 256;
        short8 vv[16];
#pragma unroll
        for (int j = 0; j < 16; ++j)
            vv[j] = *(const short8*)(base + (long)off[j] * 256);
#pragma unroll
        for (int j = 0; j < 16; ++j) {
            const float w = wgt[j];
#pragma unroll
            for (int c = 0; c < 8; ++c) acc[c] += w * bf2f((unsigned short)vv[j][c]);
        }
    }

    short8 ov;
#pragma unroll
    for (int j = 0; j < 8; ++j) ov[j] = (short)f2bf(acc[j]);
    *(short8*)(wv + (((long)b * Qn_ + q0 + qi) * 256 + h * 32 + sub * 8)) = ov;
}

// ---------------------------------------------------------------------------
extern "C" void kernel_launch(void* const* d_in, const int* in_sizes, int n_in,
                              void* d_out, int out_size, void* d_ws, size_t ws_size,
                              hipStream_t stream) {
    const float* in_feats = (const float*)d_in[0];
    const float* priors   = (const float*)d_in[1];
    const float* sfeats   = (const float*)d_in[2];
    const int*   shapes   = (const int*)d_in[3];
    const int*   starts   = (const int*)d_in[4];
    const float* W_off    = (const float*)d_in[5];
    const float* b_off    = (const float*)d_in[6];
    const float* W_attn   = (const float*)d_in[7];
    const float* b_attn   = (const float*)d_in[8];
    const float* W_val    = (const float*)d_in[9];
    const float* b_val    = (const float*)d_in[10];
    const float* W_out    = (const float*)d_in[11];
    const float* b_out    = (const float*)d_in[12];
    float* out = (float*)d_out;

    // Workspace: Wvt 128K | Wot 128K | Wcat 192K | value 44.56M | wv 4M (short)
    //            offattn 12.58M | bcat 1.5K (f32)
    short* Wvt     = (short*)d_ws;
    short* Wot     = Wvt + 65536;
    short* Wcat    = Wot + 65536;
    short* value   = Wcat + 98304;
    short* wv      = value + (long)B_ * S_ * 256;
    float* offattn = (float*)(wv + (long)B_ * Qn_ * 256);
    float* bcat    = offattn + (long)B_ * Qn_ * 384;

    prep_w<<<256, 896, 0, stream>>>(W_val, W_out, W_off, W_attn, b_off, b_attn,
                                    Wvt, Wot, Wcat, bcat);
    // value = sample_feats @ W_val + b_val   (87040 x 256), bf16 out
    gemm_ring<<<(B_ * S_) / 64, 256, 0, stream>>>(sfeats, Wvt, b_val, value);
    // offattn = in_feats @ [W_off|W_attn] + bcat  (8192 x 384), f32 out
    gemm_tile<3, 0, 1><<<dim3((B_ * Qn_) / 128, 2), 384, 0, stream>>>(
        (const void*)in_feats, Wcat, bcat, (void*)offattn, 384);
    // softmax + deformable sampling
    sampler<<<B_ * (Qn_ / 16), 512, 0, stream>>>(priors, shapes, starts,
                                                 offattn, value, wv);
    // out = wv @ W_out + b_out   (8192 x 256), f32 out
    gemm_v8<1, 1><<<(B_ * Qn_) / 64, 256, 0, stream>>>(
        (const void*)wv, Wot, b_out, (void*)out);
}

// Round 14
// 85.368 us; speedup vs baseline: 1.7318x; 1.1550x over previous
//
#include <hip/hip_runtime.h>
#include <hip/hip_bf16.h>

// Problem constants (fixed by reference)
#define B_    4
#define Qn_   2048
#define S_    21760   // 128*128 + 64*64 + 32*32 + 16*16

typedef short  bfx4    __attribute__((ext_vector_type(4)));
typedef short  short8  __attribute__((ext_vector_type(8)));
typedef float  floatx4 __attribute__((ext_vector_type(4)));

__device__ __forceinline__ unsigned short f2bf(float f) {
    unsigned int u = __builtin_bit_cast(unsigned int, f);
    u += 0x7fffu + ((u >> 16) & 1u);   // round-to-nearest-even
    return (unsigned short)(u >> 16);
}
__device__ __forceinline__ float bf2f(unsigned short h) {
    unsigned int u = ((unsigned int)h) << 16;
    return __builtin_bit_cast(float, u);
}

// packed f32x8 -> bf16x8 via v_cvt_pk_bf16_f32 (RNE, 1 instr / 2 elems)
__device__ __forceinline__ short8 cvt_pk8(floatx4 f0, floatx4 f1) {
    union { unsigned int u[4]; short8 s; } r;
    asm("v_cvt_pk_bf16_f32 %0, %1, %2" : "=v"(r.u[0]) : "v"(f0[0]), "v"(f0[1]));
    asm("v_cvt_pk_bf16_f32 %0, %1, %2" : "=v"(r.u[1]) : "v"(f0[2]), "v"(f0[3]));
    asm("v_cvt_pk_bf16_f32 %0, %1, %2" : "=v"(r.u[2]) : "v"(f1[0]), "v"(f1[1]));
    asm("v_cvt_pk_bf16_f32 %0, %1, %2" : "=v"(r.u[3]) : "v"(f1[2]), "v"(f1[3]));
    return r.s;
}

// async global->LDS, 16B per lane. lds must be WAVE-UNIFORM base (lane*16 implicit).
__device__ __forceinline__ void async16(void* lds, const void* g) {
    __builtin_amdgcn_global_load_lds(
        (const __attribute__((address_space(1))) unsigned int*)g,
        (__attribute__((address_space(3))) unsigned int*)lds, 16, 0, 0);
}

template<int N>
__device__ __forceinline__ void wait_vm_lgkm0() {
    asm volatile("s_waitcnt vmcnt(%0) lgkmcnt(0)" :: "n"(N) : "memory");
}

// ---------------------------------------------------------------------------
// Prep 1: W_val -> bf16 NxK (Wvt); [W_off|W_attn] -> bf16 NxK (Wcat); biases.
// ---------------------------------------------------------------------------
__global__ __launch_bounds__(640) void prep_w(
        const float* __restrict__ Wv,
        const float* __restrict__ Woff, const float* __restrict__ Wattn,
        const float* __restrict__ boff, const float* __restrict__ battn,
        short* __restrict__ Wvt, short* __restrict__ Wcat,
        float* __restrict__ bcat) {
    const int k = blockIdx.x;      // 0..255
    const int t = threadIdx.x;
    if (t < 256) {
        Wvt[t * 256 + k] = (short)f2bf(Wv[k * 256 + t]);
    } else {
        const int n = t - 256;     // 0..383
        const float w = (n < 256) ? Woff[k * 256 + n] : Wattn[k * 128 + (n - 256)];
        Wcat[n * 256 + k] = (short)f2bf(w);
    }
    if (blockIdx.x == 0 && t < 384)
        bcat[t] = (t < 256) ? boff[t] : battn[t - 256];
}

// ---------------------------------------------------------------------------
// Prep 2: W_out (256x256 f32, KxN) -> bf16 FRAGMENT order (for sampler_out):
//   Wf[((kc*16 + nf)*64 + lane)*8 + j] = W[kc*32 + (lane>>4)*8 + j][nf*16 + (lane&15)]
// ---------------------------------------------------------------------------
__global__ __launch_bounds__(1024) void prep_wfrag(const float* __restrict__ W,
                                                   short* __restrict__ Wf) {
    const int g = blockIdx.x * 1024 + threadIdx.x;   // 0..65535
    const int j  = g & 7;
    const int l  = (g >> 3) & 63;
    const int nf = (g >> 9) & 15;
    const int kc = g >> 13;
    const int k = kc * 32 + (l >> 4) * 8 + j;
    const int n = nf * 16 + (l & 15);
    Wf[g] = (short)f2bf(W[k * 256 + n]);
}

// ---------------------------------------------------------------------------
// gemm_core: the verified v8 inner structure, parameterized.
//   BM=64 rows, BN = NF*64 cols, 4 waves (wave w: cols w*NF*16 .. +NF*16).
//   A f32, staged via reg+cvt_pk; B bf16 NxK via global_load_lds; 2-phase
//   K-loop with counted vmcnt(2) (A(k+2) stays in flight across barriers).
//   Swapped MFMA -> row-major stores: row = row0+mf*16+l16,
//   col = colbase + w*NF*16 + nf*16 + lq*4 + reg.
// ---------------------------------------------------------------------------
template<int NF, int OUT_F32>
__device__ __forceinline__ void gemm_core(
        const float* __restrict__ Av, const short* __restrict__ Bt,
        const float* __restrict__ bias, void* __restrict__ Cv,
        long row0, int Ntot, int colbase,
        short (&As)[2][2048], short (&Bs)[2][8192]) {
    const int tid  = threadIdx.x;
    const int lane = tid & 63, wave = tid >> 6;
    const int l16  = lane & 15, lq = lane >> 4;
    const int r_a = tid >> 2, c_a = tid & 3;

    floatx4 sA0[2], sA1[2];

    auto loadA = [&](int kk, int s) {
        const float* g = Av + (row0 + r_a) * 256 + kk * 32 + c_a * 8;
        sA0[s] = *(const floatx4*)g;
        sA1[s] = *(const floatx4*)(g + 4);
    };
    auto writeA = [&](int buf, int s) {
        *(short8*)&As[buf][r_a * 32 + ((c_a ^ (r_a & 3)) << 3)] = cvt_pk8(sA0[s], sA1[s]);
    };
    auto stageB = [&](int kk, int buf) {
#pragma unroll
        for (int c2 = 0; c2 < NF; ++c2) {
            const int idx = c2 * 256 + tid;
            const int col = idx >> 2, ch = idx & 3;
            const short* g = Bt + (long)col * 256 + kk * 32 + ((ch ^ (col & 3)) << 3);
            async16(&Bs[buf][(c2 * 256 + (wave << 6)) * 8], g);
        }
    };

    floatx4 acc[4][NF];
#pragma unroll
    for (int i = 0; i < 4; ++i)
#pragma unroll
        for (int j = 0; j < NF; ++j) acc[i][j] = (floatx4){0.f, 0.f, 0.f, 0.f};

    auto compute = [&](int buf) {
        short8 af[4], bv[NF];
#pragma unroll
        for (int mf = 0; mf < 4; ++mf) {
            const int r = mf * 16 + l16;
            af[mf] = *(const short8*)&As[buf][r * 32 + ((lq ^ (r & 3)) << 3)];
        }
#pragma unroll
        for (int nf = 0; nf < NF; ++nf) {
            const int r = wave * (NF * 16) + nf * 16 + l16;
            bv[nf] = *(const short8*)&Bs[buf][r * 32 + ((lq ^ (r & 3)) << 3)];
        }
#pragma unroll
        for (int mf = 0; mf < 4; ++mf)
#pragma unroll
            for (int nf = 0; nf < NF; ++nf)
                acc[mf][nf] = __builtin_amdgcn_mfma_f32_16x16x32_bf16(
                    bv[nf], af[mf], acc[mf][nf], 0, 0, 0);   // swapped -> row-major D
    };

    stageB(0, 0);
    loadA(0, 0);
    loadA(1, 1);
    writeA(0, 0);
    wait_vm_lgkm0<2>();
    __builtin_amdgcn_s_barrier();
    __builtin_amdgcn_sched_barrier(0);

#pragma unroll
    for (int k = 0; k < 7; ++k) {
        const int cur = k & 1, nxt = cur ^ 1;
        stageB(k + 1, nxt);
        if (k < 6) loadA(k + 2, k & 1);
        compute(cur);
        writeA(nxt, (k + 1) & 1);
        if (k < 6) wait_vm_lgkm0<2>();
        else       wait_vm_lgkm0<0>();
        __builtin_amdgcn_s_barrier();
        __builtin_amdgcn_sched_barrier(0);
    }
    compute(1);

#pragma unroll
    for (int mf = 0; mf < 4; ++mf) {
        const long grow = row0 + mf * 16 + l16;
#pragma unroll
        for (int nf = 0; nf < NF; ++nf) {
            const int gcol = colbase + wave * (NF * 16) + nf * 16 + lq * 4;
            const floatx4 bv4 = *(const floatx4*)(bias + gcol);
            const floatx4 v = acc[mf][nf] + bv4;
            if (OUT_F32) {
                *(floatx4*)((float*)Cv + grow * Ntot + gcol) = v;
            } else {
                bfx4 s;
#pragma unroll
                for (int r = 0; r < 4; ++r) s[r] = (short)f2bf(v[r]);
                *(bfx4*)((short*)Cv + grow * Ntot + gcol) = s;
            }
        }
    }
}

// ---------------------------------------------------------------------------
// gemm_mega: value + offattn GEMMs fused in ONE dispatch (block classes).
//   Blocks [0,128): off cols 0..255 of offattn   (core<4,1>, A=in_feats)
//   Blocks [128,256): attn cols 256..383         (core<2,1>, A=in_feats)
//   Blocks [256,1616): value tiles               (core<4,0>, A=sfeats)
//   O/T first so they overlap the value blocks' idle issue slots.
// ---------------------------------------------------------------------------
__global__ __launch_bounds__(256) void gemm_mega(
        const float* __restrict__ sfeats, const float* __restrict__ in_feats,
        const short* __restrict__ Wvt, const short* __restrict__ Wcat,
        const float* __restrict__ b_val, const float* __restrict__ bcat,
        short* __restrict__ value, float* __restrict__ offattn) {
    __shared__ short As[2][2048];    // 8 KB
    __shared__ short Bs[2][8192];    // 32 KB

    const int bid = blockIdx.x;
    if (bid < 128) {
        gemm_core<4, 1>(in_feats, Wcat, bcat, (void*)offattn,
                        (long)bid * 64, 384, 0, As, Bs);
    } else if (bid < 256) {
        gemm_core<2, 1>(in_feats, Wcat + 65536, bcat, (void*)offattn,
                        (long)(bid - 128) * 64, 384, 256, As, Bs);
    } else {
        gemm_core<4, 0>(sfeats, Wvt, b_val, (void*)value,
                        (long)(bid - 256) * 64, 256, 0, As, Bs);
    }
}

// ---------------------------------------------------------------------------
// sampler_out: softmax + deformable gather + OUT GEMM fused.
//   512 thr, 16 queries/block, grid 512.  wv kept in LDS (bf16, chunk-XOR
//   swizzled); after a barrier each of 8 waves computes 32 output cols:
//   16 reg-operand MFMAs vs fragment-ordered W_out (Wof), f32 stores.
// ---------------------------------------------------------------------------
__global__ __launch_bounds__(512) void sampler_out(
        const float* __restrict__ priors,
        const int* __restrict__ shapes, const int* __restrict__ starts,
        const float* __restrict__ offattn,
        const short* __restrict__ value,
        const short* __restrict__ Wof, const float* __restrict__ b_out,
        float* __restrict__ out) {
    __shared__ float oa_lds[16][384];
    __shared__ short wv_lds[16][256];   // 8 KB, chunk c stored at c^(row&7)
    __shared__ float pri_lds[16][4][2];
    __shared__ int   shp_lds[4][2];
    __shared__ int   st_lds[4];

    const int tid = threadIdx.x;
    const int b   = blockIdx.x >> 7;
    const int qt  = blockIdx.x & 127;
    const long q0 = (long)qt * 16;

    const float* src = offattn + ((long)b * Qn_ + q0) * 384;
    for (int i = tid; i < 16 * 384 / 4; i += 512)
        ((floatx4*)oa_lds)[i] = ((const floatx4*)src)[i];
    if (tid < 128) ((float*)pri_lds)[tid] = priors[((long)b * Qn_ + q0) * 8 + tid];
    if (tid < 8)  ((int*)shp_lds)[tid] = shapes[tid];
    if (tid < 4)  st_lds[tid] = starts[tid];
    __syncthreads();

    if (tid < 128) {
        const int qi = tid >> 3, h = tid & 7;
        float* a = &oa_lds[qi][256 + h * 16];
        float m = a[0];
        for (int i = 1; i < 16; ++i) m = fmaxf(m, a[i]);
        float s = 0.f;
        for (int i = 0; i < 16; ++i) { float e = expf(a[i] - m); a[i] = e; s += e; }
        const float inv = 1.f / s;
        for (int i = 0; i < 16; ++i) a[i] *= inv;
    }
    __syncthreads();

    // ---- sampling: thread (qi, h, sub) -> 8 channels; wv -> LDS ----
    {
        const int pairi = tid >> 2, sub = tid & 3;
        const int qi = pairi >> 3, h = pairi & 7;
        float acc[8];
#pragma unroll
        for (int j = 0; j < 8; ++j) acc[j] = 0.f;
        const short* vbase = value + (long)b * S_ * 256 + h * 32 + sub * 8;

        for (int l = 0; l < 4; ++l) {
            const int Hl = shp_lds[l][0], Wl = shp_lds[l][1];
            const int st = st_lds[l];
            const float px = pri_lds[qi][l][0], py = pri_lds[qi][l][1];
            const float invW = 1.f / (float)Wl, invH = 1.f / (float)Hl;

            float wgt[16];
            int   off[16];
#pragma unroll
            for (int p = 0; p < 4; ++p) {
                const int cb = h * 16 + l * 4 + p;
                const float ox = oa_lds[qi][cb * 2], oy = oa_lds[qi][cb * 2 + 1];
                const float lx = px + ox * invW, ly = py + oy * invH;
                const float ix = lx * (float)Wl - 0.5f, iy = ly * (float)Hl - 0.5f;
                const float x0f = floorf(ix), y0f = floorf(iy);
                const int x0 = (int)x0f, y0 = (int)y0f;
                const float fx = ix - x0f, fy = iy - y0f;
                const float awv = oa_lds[qi][256 + cb];
#pragma unroll
                for (int dy = 0; dy < 2; ++dy) {
                    const int yc = y0 + dy;
                    const float wy = dy ? fy : 1.f - fy;
                    const int yi = min(max(yc, 0), Hl - 1);
#pragma unroll
                    for (int dx = 0; dx < 2; ++dx) {
                        const int xc = x0 + dx;
                        const float wx = dx ? fx : 1.f - fx;
                        const int xi = min(max(xc, 0), Wl - 1);
                        const bool v = (xc >= 0) & (xc < Wl) & (yc >= 0) & (yc < Hl);
                        const int j = p * 4 + dy * 2 + dx;
                        wgt[j] = v ? wy * wx * awv : 0.f;
                        off[j] = yi * Wl + xi;
                    }
                }
            }
            const short* base = vbase + (long)st * 256;
            short8 vv[16];
#pragma unroll
            for (int j = 0; j < 16; ++j)
                vv[j] = *(const short8*)(base + (long)off[j] * 256);
#pragma unroll
            for (int j = 0; j < 16; ++j) {
                const float w = wgt[j];
#pragma unroll
                for (int c = 0; c < 8; ++c) acc[c] += w * bf2f((unsigned short)vv[j][c]);
            }
        }

        short8 ov;
#pragma unroll
        for (int j = 0; j < 8; ++j) ov[j] = (short)f2bf(acc[j]);
        const int chunk = (h * 4 + sub) ^ (qi & 7);       // XOR swizzle
        *(short8*)&wv_lds[qi][chunk * 8] = ov;
    }
    __syncthreads();

    // ---- out GEMM: wave w -> cols w*32 .. +31 (16 reg-operand MFMAs) ----
    {
        const int lane = tid & 63, w = tid >> 6;
        const int l16 = lane & 15, lq = lane >> 4;

        short8 bfrag[8][2];
#pragma unroll
        for (int kc = 0; kc < 8; ++kc)
#pragma unroll
            for (int nf = 0; nf < 2; ++nf)
                bfrag[kc][nf] = *(const short8*)(
                    Wof + (long)((kc * 16 + w * 2 + nf) * 64 + lane) * 8);

        short8 af[8];
#pragma unroll
        for (int kc = 0; kc < 8; ++kc) {
            const int chunk = (kc * 4 + lq) ^ (l16 & 7);
            af[kc] = *(const short8*)&wv_lds[l16][chunk * 8];
        }

        floatx4 acc2[2];
#pragma unroll
        for (int nf = 0; nf < 2; ++nf) acc2[nf] = (floatx4){0.f, 0.f, 0.f, 0.f};
#pragma unroll
        for (int kc = 0; kc < 8; ++kc)
#pragma unroll
            for (int nf = 0; nf < 2; ++nf)
                acc2[nf] = __builtin_amdgcn_mfma_f32_16x16x32_bf16(
                    bfrag[kc][nf], af[kc], acc2[nf], 0, 0, 0);  // swapped -> row-major

        float* co = out + ((long)b * Qn_ + q0 + l16) * 256 + w * 32 + lq * 4;
#pragma unroll
        for (int nf = 0; nf < 2; ++nf) {
            const floatx4 bv4 = *(const floatx4*)(b_out + w * 32 + nf * 16 + lq * 4);
            *(floatx4*)(co + nf * 16) = acc2[nf] + bv4;
        }
    }
}

// ---------------------------------------------------------------------------
extern "C" void kernel_launch(void* const* d_in, const int* in_sizes, int n_in,
                              void* d_out, int out_size, void* d_ws, size_t ws_size,
                              hipStream_t stream) {
    const float* in_feats = (const float*)d_in[0];
    const float* priors   = (const float*)d_in[1];
    const float* sfeats   = (const float*)d_in[2];
    const int*   shapes   = (const int*)d_in[3];
    const int*   starts   = (const int*)d_in[4];
    const float* W_off    = (const float*)d_in[5];
    const float* b_off    = (const float*)d_in[6];
    const float* W_attn   = (const float*)d_in[7];
    const float* b_attn   = (const float*)d_in[8];
    const float* W_val    = (const float*)d_in[9];
    const float* b_val    = (const float*)d_in[10];
    const float* W_out    = (const float*)d_in[11];
    const float* b_out    = (const float*)d_in[12];
    float* out = (float*)d_out;

    // Workspace: Wvt 128K | Wof 128K | Wcat 192K | value 44.56M (short)
    //            offattn 12.58M | bcat 1.5K (f32)
    short* Wvt     = (short*)d_ws;
    short* Wof     = Wvt + 65536;
    short* Wcat    = Wof + 65536;
    short* value   = Wcat + 98304;
    float* offattn = (float*)(value + (long)B_ * S_ * 256);
    float* bcat    = offattn + (long)B_ * Qn_ * 384;

    prep_w<<<256, 640, 0, stream>>>(W_val, W_off, W_attn, b_off, b_attn,
                                    Wvt, Wcat, bcat);
    prep_wfrag<<<64, 1024, 0, stream>>>(W_out, Wof);
    // value GEMM + offattn GEMM fused (one dispatch, block classes)
    gemm_mega<<<256 + (B_ * S_) / 64, 256, 0, stream>>>(
        sfeats, in_feats, Wvt, Wcat, b_val, bcat, value, offattn);
    // softmax + deformable sampling + out GEMM fused
    sampler_out<<<B_ * (Qn_ / 16), 512, 0, stream>>>(
        priors, shapes, starts, offattn, value, Wof, b_out, out);
}

// Round 15
// 80.814 us; speedup vs baseline: 1.8293x; 1.0563x over previous
//
#include <hip/hip_runtime.h>
#include <hip/hip_bf16.h>

// Problem constants (fixed by reference)
#define B_    4
#define Qn_   2048
#define S_    21760   // 128*128 + 64*64 + 32*32 + 16*16

typedef short  bfx4    __attribute__((ext_vector_type(4)));
typedef short  short8  __attribute__((ext_vector_type(8)));
typedef float  floatx4 __attribute__((ext_vector_type(4)));

__device__ __forceinline__ unsigned short f2bf(float f) {
    unsigned int u = __builtin_bit_cast(unsigned int, f);
    u += 0x7fffu + ((u >> 16) & 1u);   // round-to-nearest-even
    return (unsigned short)(u >> 16);
}
__device__ __forceinline__ float bf2f(unsigned short h) {
    unsigned int u = ((unsigned int)h) << 16;
    return __builtin_bit_cast(float, u);
}

// packed f32x8 -> bf16x8 via v_cvt_pk_bf16_f32 (RNE, 1 instr / 2 elems)
__device__ __forceinline__ short8 cvt_pk8(floatx4 f0, floatx4 f1) {
    union { unsigned int u[4]; short8 s; } r;
    asm("v_cvt_pk_bf16_f32 %0, %1, %2" : "=v"(r.u[0]) : "v"(f0[0]), "v"(f0[1]));
    asm("v_cvt_pk_bf16_f32 %0, %1, %2" : "=v"(r.u[1]) : "v"(f0[2]), "v"(f0[3]));
    asm("v_cvt_pk_bf16_f32 %0, %1, %2" : "=v"(r.u[2]) : "v"(f1[0]), "v"(f1[1]));
    asm("v_cvt_pk_bf16_f32 %0, %1, %2" : "=v"(r.u[3]) : "v"(f1[2]), "v"(f1[3]));
    return r.s;
}

// async global->LDS, 16B per lane. lds must be WAVE-UNIFORM base (lane*16 implicit).
__device__ __forceinline__ void async16(void* lds, const void* g) {
    __builtin_amdgcn_global_load_lds(
        (const __attribute__((address_space(1))) unsigned int*)g,
        (__attribute__((address_space(3))) unsigned int*)lds, 16, 0, 0);
}

template<int N>
__device__ __forceinline__ void wait_vm_lgkm0() {
    asm volatile("s_waitcnt vmcnt(%0) lgkmcnt(0)" :: "n"(N) : "memory");
}

// ---------------------------------------------------------------------------
// prep_all: ONE dispatch for all weight prep.
//   Blocks [0,256): k = bid.  t<256: Wvt (W_val -> bf16 NxK);
//     256<=t<640: Wcat ([W_off|W_attn] -> bf16 NxK); bid==0&&t<384: bcat.
//   Blocks [256,320): W_out -> bf16 FRAGMENT order Wof:
//     Wof[((kc*16+nf)*64+l)*8+j] = Wo[(kc*32+(l>>4)*8+j)*256 + nf*16+(l&15)]
// ---------------------------------------------------------------------------
__global__ __launch_bounds__(1024) void prep_all(
        const float* __restrict__ Wv, const float* __restrict__ Wo,
        const float* __restrict__ Woff, const float* __restrict__ Wattn,
        const float* __restrict__ boff, const float* __restrict__ battn,
        short* __restrict__ Wvt, short* __restrict__ Wcat,
        short* __restrict__ Wof, float* __restrict__ bcat) {
    const int bid = blockIdx.x;
    const int t   = threadIdx.x;
    if (bid < 256) {
        const int k = bid;
        if (t < 256) {
            Wvt[t * 256 + k] = (short)f2bf(Wv[k * 256 + t]);
        } else if (t < 640) {
            const int n = t - 256;     // 0..383
            const float w = (n < 256) ? Woff[k * 256 + n] : Wattn[k * 128 + (n - 256)];
            Wcat[n * 256 + k] = (short)f2bf(w);
        }
        if (bid == 0 && t < 384)
            bcat[t] = (t < 256) ? boff[t] : battn[t - 256];
    } else {
        const int g = (bid - 256) * 1024 + t;   // 0..65535
        const int j  = g & 7;
        const int l  = (g >> 3) & 63;
        const int nf = (g >> 9) & 15;
        const int kc = g >> 13;
        const int k = kc * 32 + (l >> 4) * 8 + j;
        const int n = nf * 16 + (l & 15);
        Wof[g] = (short)f2bf(Wo[k * 256 + n]);
    }
}

// ---------------------------------------------------------------------------
// gemm_core: the verified v8 inner structure, parameterized.
//   BM=64 rows, BN = NF*64 cols, 4 waves (wave w: cols w*NF*16 .. +NF*16).
//   A f32, staged via reg+cvt_pk; B bf16 NxK via global_load_lds; 2-phase
//   K-loop with counted vmcnt(2) (A(k+2) stays in flight across barriers).
//   Swapped MFMA -> row-major stores.
// ---------------------------------------------------------------------------
template<int NF, int OUT_F32>
__device__ __forceinline__ void gemm_core(
        const float* __restrict__ Av, const short* __restrict__ Bt,
        const float* __restrict__ bias, void* __restrict__ Cv,
        long row0, int Ntot, int colbase,
        short (&As)[2][2048], short (&Bs)[2][8192]) {
    const int tid  = threadIdx.x;
    const int lane = tid & 63, wave = tid >> 6;
    const int l16  = lane & 15, lq = lane >> 4;
    const int r_a = tid >> 2, c_a = tid & 3;

    floatx4 sA0[2], sA1[2];

    auto loadA = [&](int kk, int s) {
        const float* g = Av + (row0 + r_a) * 256 + kk * 32 + c_a * 8;
        sA0[s] = *(const floatx4*)g;
        sA1[s] = *(const floatx4*)(g + 4);
    };
    auto writeA = [&](int buf, int s) {
        *(short8*)&As[buf][r_a * 32 + ((c_a ^ (r_a & 3)) << 3)] = cvt_pk8(sA0[s], sA1[s]);
    };
    auto stageB = [&](int kk, int buf) {
#pragma unroll
        for (int c2 = 0; c2 < NF; ++c2) {
            const int idx = c2 * 256 + tid;
            const int col = idx >> 2, ch = idx & 3;
            const short* g = Bt + (long)col * 256 + kk * 32 + ((ch ^ (col & 3)) << 3);
            async16(&Bs[buf][(c2 * 256 + (wave << 6)) * 8], g);
        }
    };

    floatx4 acc[4][NF];
#pragma unroll
    for (int i = 0; i < 4; ++i)
#pragma unroll
        for (int j = 0; j < NF; ++j) acc[i][j] = (floatx4){0.f, 0.f, 0.f, 0.f};

    auto compute = [&](int buf) {
        short8 af[4], bv[NF];
#pragma unroll
        for (int mf = 0; mf < 4; ++mf) {
            const int r = mf * 16 + l16;
            af[mf] = *(const short8*)&As[buf][r * 32 + ((lq ^ (r & 3)) << 3)];
        }
#pragma unroll
        for (int nf = 0; nf < NF; ++nf) {
            const int r = wave * (NF * 16) + nf * 16 + l16;
            bv[nf] = *(const short8*)&Bs[buf][r * 32 + ((lq ^ (r & 3)) << 3)];
        }
#pragma unroll
        for (int mf = 0; mf < 4; ++mf)
#pragma unroll
            for (int nf = 0; nf < NF; ++nf)
                acc[mf][nf] = __builtin_amdgcn_mfma_f32_16x16x32_bf16(
                    bv[nf], af[mf], acc[mf][nf], 0, 0, 0);   // swapped -> row-major D
    };

    stageB(0, 0);
    loadA(0, 0);
    loadA(1, 1);
    writeA(0, 0);
    wait_vm_lgkm0<2>();
    __builtin_amdgcn_s_barrier();
    __builtin_amdgcn_sched_barrier(0);

#pragma unroll
    for (int k = 0; k < 7; ++k) {
        const int cur = k & 1, nxt = cur ^ 1;
        stageB(k + 1, nxt);
        if (k < 6) loadA(k + 2, k & 1);
        compute(cur);
        writeA(nxt, (k + 1) & 1);
        if (k < 6) wait_vm_lgkm0<2>();
        else       wait_vm_lgkm0<0>();
        __builtin_amdgcn_s_barrier();
        __builtin_amdgcn_sched_barrier(0);
    }
    compute(1);

#pragma unroll
    for (int mf = 0; mf < 4; ++mf) {
        const long grow = row0 + mf * 16 + l16;
#pragma unroll
        for (int nf = 0; nf < NF; ++nf) {
            const int gcol = colbase + wave * (NF * 16) + nf * 16 + lq * 4;
            const floatx4 bv4 = *(const floatx4*)(bias + gcol);
            const floatx4 v = acc[mf][nf] + bv4;
            if (OUT_F32) {
                *(floatx4*)((float*)Cv + grow * Ntot + gcol) = v;
            } else {
                bfx4 s;
#pragma unroll
                for (int r = 0; r < 4; ++r) s[r] = (short)f2bf(v[r]);
                *(bfx4*)((short*)Cv + grow * Ntot + gcol) = s;
            }
        }
    }
}

// ---------------------------------------------------------------------------
// gemm_mega: value + offattn GEMMs fused (block classes), value FIRST.
//   Blocks [0,1360): value tiles                 (core<4,0>, A=sfeats)
//   Blocks [1360,1488): off cols 0..255          (core<4,1>, A=in_feats)
//   Blocks [1488,1616): attn cols 256..383       (core<2,1>, A=in_feats)
//   __launch_bounds__(256,4): VGPR 80 <= 128 and LDS 40KB allow 4 blocks/CU;
//   r14's occupancy read ~24% (2 blocks) -- request full residency.
// ---------------------------------------------------------------------------
__global__ __launch_bounds__(256, 4) void gemm_mega(
        const float* __restrict__ sfeats, const float* __restrict__ in_feats,
        const short* __restrict__ Wvt, const short* __restrict__ Wcat,
        const float* __restrict__ b_val, const float* __restrict__ bcat,
        short* __restrict__ value, float* __restrict__ offattn) {
    __shared__ short As[2][2048];    // 8 KB
    __shared__ short Bs[2][8192];    // 32 KB

    const int bid = blockIdx.x;
    const int nval = (B_ * S_) / 64;                 // 1360
    if (bid < nval) {
        gemm_core<4, 0>(sfeats, Wvt, b_val, (void*)value,
                        (long)bid * 64, 256, 0, As, Bs);
    } else if (bid < nval + 128) {
        gemm_core<4, 1>(in_feats, Wcat, bcat, (void*)offattn,
                        (long)(bid - nval) * 64, 384, 0, As, Bs);
    } else {
        gemm_core<2, 1>(in_feats, Wcat + 65536, bcat, (void*)offattn,
                        (long)(bid - nval - 128) * 64, 384, 256, As, Bs);
    }
}

// ---------------------------------------------------------------------------
// sampler_out: softmax + deformable gather + OUT GEMM fused (r14 verified).
// ---------------------------------------------------------------------------
__global__ __launch_bounds__(512) void sampler_out(
        const float* __restrict__ priors,
        const int* __restrict__ shapes, const int* __restrict__ starts,
        const float* __restrict__ offattn,
        const short* __restrict__ value,
        const short* __restrict__ Wof, const float* __restrict__ b_out,
        float* __restrict__ out) {
    __shared__ float oa_lds[16][384];
    __shared__ short wv_lds[16][256];   // 8 KB, chunk c stored at c^(row&7)
    __shared__ float pri_lds[16][4][2];
    __shared__ int   shp_lds[4][2];
    __shared__ int   st_lds[4];

    const int tid = threadIdx.x;
    const int b   = blockIdx.x >> 7;
    const int qt  = blockIdx.x & 127;
    const long q0 = (long)qt * 16;

    const float* src = offattn + ((long)b * Qn_ + q0) * 384;
    for (int i = tid; i < 16 * 384 / 4; i += 512)
        ((floatx4*)oa_lds)[i] = ((const floatx4*)src)[i];
    if (tid < 128) ((float*)pri_lds)[tid] = priors[((long)b * Qn_ + q0) * 8 + tid];
    if (tid < 8)  ((int*)shp_lds)[tid] = shapes[tid];
    if (tid < 4)  st_lds[tid] = starts[tid];
    __syncthreads();

    if (tid < 128) {
        const int qi = tid >> 3, h = tid & 7;
        float* a = &oa_lds[qi][256 + h * 16];
        float m = a[0];
        for (int i = 1; i < 16; ++i) m = fmaxf(m, a[i]);
        float s = 0.f;
        for (int i = 0; i < 16; ++i) { float e = expf(a[i] - m); a[i] = e; s += e; }
        const float inv = 1.f / s;
        for (int i = 0; i < 16; ++i) a[i] *= inv;
    }
    __syncthreads();

    // ---- sampling: thread (qi, h, sub) -> 8 channels; wv -> LDS ----
    {
        const int pairi = tid >> 2, sub = tid & 3;
        const int qi = pairi >> 3, h = pairi & 7;
        float acc[8];
#pragma unroll
        for (int j = 0; j < 8; ++j) acc[j] = 0.f;
        const short* vbase = value + (long)b * S_ * 256 + h * 32 + sub * 8;

        for (int l = 0; l < 4; ++l) {
            const int Hl = shp_lds[l][0], Wl = shp_lds[l][1];
            const int st = st_lds[l];
            const float px = pri_lds[qi][l][0], py = pri_lds[qi][l][1];
            const float invW = 1.f / (float)Wl, invH = 1.f / (float)Hl;

            float wgt[16];
            int   off[16];
#pragma unroll
            for (int p = 0; p < 4; ++p) {
                const int cb = h * 16 + l * 4 + p;
                const float ox = oa_lds[qi][cb * 2], oy = oa_lds[qi][cb * 2 + 1];
                const float lx = px + ox * invW, ly = py + oy * invH;
                const float ix = lx * (float)Wl - 0.5f, iy = ly * (float)Hl - 0.5f;
                const float x0f = floorf(ix), y0f = floorf(iy);
                const int x0 = (int)x0f, y0 = (int)y0f;
                const float fx = ix - x0f, fy = iy - y0f;
                const float awv = oa_lds[qi][256 + cb];
#pragma unroll
                for (int dy = 0; dy < 2; ++dy) {
                    const int yc = y0 + dy;
                    const float wy = dy ? fy : 1.f - fy;
                    const int yi = min(max(yc, 0), Hl - 1);
#pragma unroll
                    for (int dx = 0; dx < 2; ++dx) {
                        const int xc = x0 + dx;
                        const float wx = dx ? fx : 1.f - fx;
                        const int xi = min(max(xc, 0), Wl - 1);
                        const bool v = (xc >= 0) & (xc < Wl) & (yc >= 0) & (yc < Hl);
                        const int j = p * 4 + dy * 2 + dx;
                        wgt[j] = v ? wy * wx * awv : 0.f;
                        off[j] = yi * Wl + xi;
                    }
                }
            }
            const short* base = vbase + (long)st * 256;
            short8 vv[16];
#pragma unroll
            for (int j = 0; j < 16; ++j)
                vv[j] = *(const short8*)(base + (long)off[j] * 256);
#pragma unroll
            for (int j = 0; j < 16; ++j) {
                const float w = wgt[j];
#pragma unroll
                for (int c = 0; c < 8; ++c) acc[c] += w * bf2f((unsigned short)vv[j][c]);
            }
        }

        short8 ov;
#pragma unroll
        for (int j = 0; j < 8; ++j) ov[j] = (short)f2bf(acc[j]);
        const int chunk = (h * 4 + sub) ^ (qi & 7);       // XOR swizzle
        *(short8*)&wv_lds[qi][chunk * 8] = ov;
    }
    __syncthreads();

    // ---- out GEMM: wave w -> cols w*32 .. +31 (16 reg-operand MFMAs) ----
    {
        const int lane = tid & 63, w = tid >> 6;
        const int l16 = lane & 15, lq = lane >> 4;

        short8 bfrag[8][2];
#pragma unroll
        for (int kc = 0; kc < 8; ++kc)
#pragma unroll
            for (int nf = 0; nf < 2; ++nf)
                bfrag[kc][nf] = *(const short8*)(
                    Wof + (long)((kc * 16 + w * 2 + nf) * 64 + lane) * 8);

        short8 af[8];
#pragma unroll
        for (int kc = 0; kc < 8; ++kc) {
            const int chunk = (kc * 4 + lq) ^ (l16 & 7);
            af[kc] = *(const short8*)&wv_lds[l16][chunk * 8];
        }

        floatx4 acc2[2];
#pragma unroll
        for (int nf = 0; nf < 2; ++nf) acc2[nf] = (floatx4){0.f, 0.f, 0.f, 0.f};
#pragma unroll
        for (int kc = 0; kc < 8; ++kc)
#pragma unroll
            for (int nf = 0; nf < 2; ++nf)
                acc2[nf] = __builtin_amdgcn_mfma_f32_16x16x32_bf16(
                    bfrag[kc][nf], af[kc], acc2[nf], 0, 0, 0);  // swapped -> row-major

        float* co = out + ((long)b * Qn_ + q0 + l16) * 256 + w * 32 + lq * 4;
#pragma unroll
        for (int nf = 0; nf < 2; ++nf) {
            const floatx4 bv4 = *(const floatx4*)(b_out + w * 32 + nf * 16 + lq * 4);
            *(floatx4*)(co + nf * 16) = acc2[nf] + bv4;
        }
    }
}

// ---------------------------------------------------------------------------
extern "C" void kernel_launch(void* const* d_in, const int* in_sizes, int n_in,
                              void* d_out, int out_size, void* d_ws, size_t ws_size,
                              hipStream_t stream) {
    const float* in_feats = (const float*)d_in[0];
    const float* priors   = (const float*)d_in[1];
    const float* sfeats   = (const float*)d_in[2];
    const int*   shapes   = (const int*)d_in[3];
    const int*   starts   = (const int*)d_in[4];
    const float* W_off    = (const float*)d_in[5];
    const float* b_off    = (const float*)d_in[6];
    const float* W_attn   = (const float*)d_in[7];
    const float* b_attn   = (const float*)d_in[8];
    const float* W_val    = (const float*)d_in[9];
    const float* b_val    = (const float*)d_in[10];
    const float* W_out    = (const float*)d_in[11];
    const float* b_out    = (const float*)d_in[12];
    float* out = (float*)d_out;

    // Workspace: Wvt 128K | Wof 128K | Wcat 192K | value 44.56M (short)
    //            offattn 12.58M | bcat 1.5K (f32)
    short* Wvt     = (short*)d_ws;
    short* Wof     = Wvt + 65536;
    short* Wcat    = Wof + 65536;
    short* value   = Wcat + 98304;
    float* offattn = (float*)(value + (long)B_ * S_ * 256);
    float* bcat    = offattn + (long)B_ * Qn_ * 384;

    // all weight prep in one dispatch
    prep_all<<<320, 1024, 0, stream>>>(W_val, W_out, W_off, W_attn, b_off, b_attn,
                                       Wvt, Wcat, Wof, bcat);
    // value GEMM + offattn GEMM fused (one dispatch, value blocks first)
    gemm_mega<<<256 + (B_ * S_) / 64, 256, 0, stream>>>(
        sfeats, in_feats, Wvt, Wcat, b_val, bcat, value, offattn);
    // softmax + deformable sampling + out GEMM fused
    sampler_out<<<B_ * (Qn_ / 16), 512, 0, stream>>>(
        priors, shapes, starts, offattn, value, Wof, b_out, out);
}